// Round 1
// baseline (297.423 us; speedup 1.0000x reference)
//
#include <hip/hip_runtime.h>
#include <math.h>

namespace {

constexpr int LNUM = 2097152;        // L
constexpr int NROW = 5;              // N
constexpr int WID = 11;              // max-pool width
constexpr int HALO = WID / 2;        // 5
constexpr int TPB = 256;
constexpr int CHUNK = 4096;          // elements per block
constexpr int EPT = CHUNK / TPB;     // 16
constexpr int NCHUNK = LNUM / CHUNK; // 512
constexpr int NSERIES = 2 * NROW;    // 10 (sig-major: 0..4 rppg, 5..9 ppg)
constexpr int NBLK = NSERIES * NCHUNK;

struct Stats { double sum; double sumsq; double sumpk; unsigned long long npk; };
struct Agg { int first; int last; int c; double s; };

__device__ inline Agg combine(const Agg& a, const Agg& b) {
  // ordered segment-concat monoid: a is the LEFT segment, b the RIGHT.
  Agg r;
  r.first = (a.first >= 0) ? a.first : b.first;
  r.last  = (b.last >= 0) ? b.last : a.last;
  r.s = a.s + b.s;
  r.c = a.c + b.c;
  if (a.last >= 0 && b.first >= 0) {
    r.s += 1.0 / (double)(b.first - a.last);
    r.c += 1;
  }
  return r;
}

// Pass 1: per-row sum, sumsq, and (raw-domain) peak-value sum + peak count.
__global__ void stats_kernel(const float* __restrict__ rppg,
                             const float* __restrict__ ppg,
                             Stats* __restrict__ stats) {
  __shared__ float sh[CHUNK + 2 * HALO];
  const int bid = blockIdx.x;
  const int sig = bid / (NROW * NCHUNK);
  const int rem = bid - sig * (NROW * NCHUNK);
  const int row = rem / NCHUNK;
  const int chunk = rem - row * NCHUNK;
  const float* x = (sig == 0 ? rppg : ppg) + (size_t)row * LNUM;
  const int base = chunk * CHUNK;

  for (int i = threadIdx.x; i < CHUNK + 2 * HALO; i += TPB) {
    int g = base - HALO + i;
    sh[i] = (g >= 0 && g < LNUM) ? x[g] : -INFINITY;
  }
  __syncthreads();

  double tsum = 0.0, tsq = 0.0, tpk = 0.0;
  int tnpk = 0;
  for (int j = 0; j < EPT; ++j) {
    int pl = j * TPB + threadIdx.x;  // strided: conflict-free LDS
    float v = sh[pl + HALO];
    float w = sh[pl];
#pragma unroll
    for (int k = 1; k < WID; ++k) w = fmaxf(w, sh[pl + k]);
    tsum += (double)v;
    tsq += (double)v * (double)v;
    if (v == w) { ++tnpk; tpk += (double)v; }
  }

  __shared__ double rs[TPB];
  __shared__ double rq[TPB];
  __shared__ double rp[TPB];
  __shared__ int rn[TPB];
  rs[threadIdx.x] = tsum; rq[threadIdx.x] = tsq;
  rp[threadIdx.x] = tpk;  rn[threadIdx.x] = tnpk;
  __syncthreads();
  for (int s = TPB / 2; s > 0; s >>= 1) {
    if (threadIdx.x < s) {
      rs[threadIdx.x] += rs[threadIdx.x + s];
      rq[threadIdx.x] += rq[threadIdx.x + s];
      rp[threadIdx.x] += rp[threadIdx.x + s];
      rn[threadIdx.x] += rn[threadIdx.x + s];
    }
    __syncthreads();
  }
  if (threadIdx.x == 0) {
    Stats* st = stats + sig * NROW + row;
    atomicAdd(&st->sum, rs[0]);
    atomicAdd(&st->sumsq, rq[0]);
    atomicAdd(&st->sumpk, rp[0]);
    atomicAdd(&st->npk, (unsigned long long)rn[0]);
  }
}

// Tiny: raw-domain amplitude threshold per row.
// x_norm > mean_pk_norm/2  <=>  x > (mu + mean_pk_raw)/2   (sd > 0)
__global__ void thresh_kernel(const Stats* __restrict__ stats,
                              double* __restrict__ thr) {
  int i = threadIdx.x;
  if (i < NSERIES) {
    double mu = stats[i].sum / (double)LNUM;
    double mean_pk = stats[i].sumpk / (double)stats[i].npk;
    thr[i] = 0.5 * (mu + mean_pk);
  }
}

// Pass 2: per-chunk ordered gap aggregates.
__global__ void gap_kernel(const float* __restrict__ rppg,
                           const float* __restrict__ ppg,
                           const double* __restrict__ thr,
                           int* __restrict__ cfirst, int* __restrict__ clast,
                           double* __restrict__ csum, int* __restrict__ ccnt) {
  __shared__ float sh[CHUNK + 2 * HALO];
  __shared__ unsigned char msk[CHUNK];
  __shared__ Agg aggs[TPB];
  const int bid = blockIdx.x;
  const int sig = bid / (NROW * NCHUNK);
  const int rem = bid - sig * (NROW * NCHUNK);
  const int row = rem / NCHUNK;
  const int chunk = rem - row * NCHUNK;
  const float* x = (sig == 0 ? rppg : ppg) + (size_t)row * LNUM;
  const int base = chunk * CHUNK;
  const float th = (float)thr[sig * NROW + row];

  for (int i = threadIdx.x; i < CHUNK + 2 * HALO; i += TPB) {
    int g = base - HALO + i;
    sh[i] = (g >= 0 && g < LNUM) ? x[g] : -INFINITY;
  }
  __syncthreads();

  // strided mask computation (conflict-free LDS reads)
  for (int j = 0; j < EPT; ++j) {
    int pl = j * TPB + threadIdx.x;
    float v = sh[pl + HALO];
    float w = sh[pl];
#pragma unroll
    for (int k = 1; k < WID; ++k) w = fmaxf(w, sh[pl + k]);
    msk[pl] = (v == w && v > th) ? (unsigned char)1 : (unsigned char)0;
  }
  __syncthreads();

  // contiguous per-thread segment scan over the mask
  Agg a; a.first = -1; a.last = -1; a.c = 0; a.s = 0.0;
  const int lbase = threadIdx.x * EPT;
  for (int j = 0; j < EPT; ++j) {
    if (msk[lbase + j]) {
      int p = base + lbase + j;  // global index within the row
      if (a.last >= 0) { a.s += 1.0 / (double)(p - a.last); ++a.c; }
      else a.first = p;
      a.last = p;
    }
  }
  aggs[threadIdx.x] = a;
  __syncthreads();
  // ORDERED tree combine (adjacent segments; op is non-commutative)
  for (int s = 1; s < TPB; s <<= 1) {
    if ((threadIdx.x & (2 * s - 1)) == 0)
      aggs[threadIdx.x] = combine(aggs[threadIdx.x], aggs[threadIdx.x + s]);
    __syncthreads();
  }
  if (threadIdx.x == 0) {
    cfirst[bid] = aggs[0].first;
    clast[bid] = aggs[0].last;
    csum[bid] = aggs[0].s;
    ccnt[bid] = aggs[0].c;
  }
}

// Combine the 512 chunk aggregates of each row (in order) -> hr per row.
__global__ void finalize_rows(const int* __restrict__ cfirst,
                              const int* __restrict__ clast,
                              const double* __restrict__ csum,
                              const int* __restrict__ ccnt,
                              const int* __restrict__ fsp,
                              double* __restrict__ hr) {
  __shared__ Agg aggs[NCHUNK];
  const int sr = blockIdx.x;  // 0..9
  const int t = threadIdx.x;  // 0..511
  Agg a;
  a.first = cfirst[sr * NCHUNK + t];
  a.last  = clast[sr * NCHUNK + t];
  a.s     = csum[sr * NCHUNK + t];
  a.c     = ccnt[sr * NCHUNK + t];
  aggs[t] = a;
  __syncthreads();
  for (int s = 1; s < NCHUNK; s <<= 1) {
    if ((t & (2 * s - 1)) == 0)
      aggs[t] = combine(aggs[t], aggs[t + s]);
    __syncthreads();
  }
  if (t == 0) {
    double fs = (double)fsp[0];
    hr[sr] = 60.0 * fs * aggs[0].s / (double)aggs[0].c;
  }
}

__global__ void final_kernel(const double* __restrict__ hr,
                             float* __restrict__ out) {
  double acc = 0.0;
  for (int r = 0; r < NROW; ++r) {
    double rh = hr[r];          // rppg rows (sig 0)
    double ph = hr[NROW + r];   // ppg rows (sig 1)
    acc += fabs(ph - rh) / ph;
  }
  out[0] = (float)(acc / (double)NROW);
}

}  // namespace

extern "C" void kernel_launch(void* const* d_in, const int* in_sizes, int n_in,
                              void* d_out, int out_size, void* d_ws, size_t ws_size,
                              hipStream_t stream) {
  const float* rppg = (const float*)d_in[0];
  const float* ppg  = (const float*)d_in[1];
  const int* fsp    = (const int*)d_in[2];
  float* out        = (float*)d_out;
  char* ws          = (char*)d_ws;

  // ws layout (all 8B-aligned)
  Stats* stats  = (Stats*)(ws + 0);          // 320 B
  double* thr   = (double*)(ws + 512);       // 80 B
  double* hr    = (double*)(ws + 1024);      // 80 B
  double* csum  = (double*)(ws + 2048);      // 40960 B
  int* cfirst   = (int*)(ws + 2048 + 40960);            // 20480 B
  int* clast    = (int*)(ws + 2048 + 40960 + 20480);    // 20480 B
  int* ccnt     = (int*)(ws + 2048 + 40960 + 40960);    // 20480 B
  // total ~104 KB of ws

  hipMemsetAsync(stats, 0, sizeof(Stats) * NSERIES, stream);
  stats_kernel<<<NBLK, TPB, 0, stream>>>(rppg, ppg, stats);
  thresh_kernel<<<1, 64, 0, stream>>>(stats, thr);
  gap_kernel<<<NBLK, TPB, 0, stream>>>(rppg, ppg, thr, cfirst, clast, csum, ccnt);
  finalize_rows<<<NSERIES, NCHUNK, 0, stream>>>(cfirst, clast, csum, ccnt, fsp, hr);
  final_kernel<<<1, 1, 0, stream>>>(hr, out);
  (void)in_sizes; (void)n_in; (void)out_size; (void)ws_size;
}

// Round 2
// 173.397 us; speedup vs baseline: 1.7153x; 1.7153x over previous
//
#include <hip/hip_runtime.h>
#include <math.h>

namespace {

constexpr int LNUM = 2097152;        // L
constexpr int NROW = 5;              // N
constexpr int TPB = 256;
constexpr int CHUNK = 4096;          // elements per block
constexpr int NCHUNK = LNUM / CHUNK; // 512
constexpr int NSERIES = 2 * NROW;    // 10 (sig-major: 0..4 rppg, 5..9 ppg)
constexpr int NBLK = NSERIES * NCHUNK;  // 5120
constexpr int NWAVE = TPB / 64;      // 4
constexpr int SEG = CHUNK / NWAVE;   // 1024 contiguous elements per wave
constexpr int ITER = SEG / 64;       // 16

struct Agg { int first; int last; int c; double s; };

__device__ inline Agg combine(const Agg& a, const Agg& b) {
  // ordered segment-concat monoid: a LEFT, b RIGHT (non-commutative)
  Agg r;
  r.first = (a.first >= 0) ? a.first : b.first;
  r.last  = (b.last >= 0) ? b.last : a.last;
  r.s = a.s + b.s;
  r.c = a.c + b.c;
  if (a.last >= 0 && b.first >= 0) {
    r.s += 1.0 / (double)(b.first - a.last);
    r.c += 1;
  }
  return r;
}

__device__ inline void stage(const float* __restrict__ x, int base, float* sh) {
  // stage [base-8, base+CHUNK+8) into sh[0..CHUNK+16); element p -> sh[p+8]
  if (base >= 8 && base + CHUNK + 8 <= LNUM) {
    const float4* xv = (const float4*)(x + base - 8);  // 16B aligned (base%4096==0)
    float4* shv = (float4*)sh;
    for (int i = threadIdx.x; i < CHUNK / 4 + 4; i += TPB) shv[i] = xv[i];
  } else {
    for (int i = threadIdx.x; i < CHUNK + 16; i += TPB) {
      int g = base - 8 + i;
      sh[i] = (g >= 0 && g < LNUM) ? x[g] : -INFINITY;
    }
  }
}

// Pass 1: per-chunk partials {sum, peak-value-sum, peak-count}. No atomics.
// (sumsq dropped: std cancels out of the raw-domain threshold.)
__global__ __launch_bounds__(TPB) void stats_kernel(
    const float* __restrict__ rppg, const float* __restrict__ ppg,
    double* __restrict__ psum, double* __restrict__ ppk,
    int* __restrict__ pnpk) {
  __shared__ float sh[CHUNK + 16];
  __shared__ double wsum[NWAVE], wpk[NWAVE];
  __shared__ int wn[NWAVE];
  const int bid = blockIdx.x;
  const int sig = bid / (NROW * NCHUNK);
  const int rem = bid - sig * (NROW * NCHUNK);
  const int row = rem / NCHUNK;
  const int chunk = rem - row * NCHUNK;
  const float* x = (sig == 0 ? rppg : ppg) + (size_t)row * LNUM;
  const int base = chunk * CHUNK;

  stage(x, base, sh);
  __syncthreads();

  const int lane = threadIdx.x & 63;
  const int wid = threadIdx.x >> 6;
  const int woff = wid * SEG;
  double tsum = 0.0, tpk = 0.0;
  int tn = 0;
  for (int j = 0; j < ITER; ++j) {
    int pl = woff + j * 64 + lane;  // consecutive lanes -> consecutive addrs
    float v = sh[pl + 8];
    float w = sh[pl + 3];
#pragma unroll
    for (int k = 1; k < 11; ++k) w = fmaxf(w, sh[pl + 3 + k]);
    tsum += (double)v;
    if (v == w) { tpk += (double)v; ++tn; }
  }
  for (int off = 32; off > 0; off >>= 1) {
    tsum += __shfl_down(tsum, off);
    tpk  += __shfl_down(tpk, off);
    tn   += __shfl_down(tn, off);
  }
  if (lane == 0) { wsum[wid] = tsum; wpk[wid] = tpk; wn[wid] = tn; }
  __syncthreads();
  if (threadIdx.x == 0) {
    double S = 0.0, P = 0.0; int Nn = 0;
    for (int wq = 0; wq < NWAVE; ++wq) { S += wsum[wq]; P += wpk[wq]; Nn += wn[wq]; }
    psum[bid] = S; ppk[bid] = P; pnpk[bid] = Nn;
  }
}

// Stage 1b: reduce 512 chunk partials per row -> raw-domain threshold.
// x_norm > mean_pk_norm/2  <=>  x > (mu + mean_pk_raw)/2
__global__ void thresh_kernel(const double* __restrict__ psum,
                              const double* __restrict__ ppk,
                              const int* __restrict__ pnpk,
                              double* __restrict__ thr) {
  __shared__ double rs[NCHUNK], rp[NCHUNK];
  __shared__ long long rn[NCHUNK];
  const int row = blockIdx.x;
  const int t = threadIdx.x;
  rs[t] = psum[row * NCHUNK + t];
  rp[t] = ppk[row * NCHUNK + t];
  rn[t] = pnpk[row * NCHUNK + t];
  __syncthreads();
  for (int s = NCHUNK / 2; s > 0; s >>= 1) {
    if (t < s) { rs[t] += rs[t + s]; rp[t] += rp[t + s]; rn[t] += rn[t + s]; }
    __syncthreads();
  }
  if (t == 0) {
    double mu = rs[0] / (double)LNUM;
    double mpk = rp[0] / (double)rn[0];
    thr[row] = 0.5 * (mu + mpk);
  }
}

// Pass 2: ballot-based ordered gap scan; one Agg per chunk. No LDS mask.
__global__ __launch_bounds__(TPB) void gap_kernel(
    const float* __restrict__ rppg, const float* __restrict__ ppg,
    const double* __restrict__ thr,
    int* __restrict__ cfirst, int* __restrict__ clast,
    double* __restrict__ csum, int* __restrict__ ccnt) {
  __shared__ float sh[CHUNK + 16];
  __shared__ Agg waggs[NWAVE];
  const int bid = blockIdx.x;
  const int sig = bid / (NROW * NCHUNK);
  const int rem = bid - sig * (NROW * NCHUNK);
  const int row = rem / NCHUNK;
  const int chunk = rem - row * NCHUNK;
  const float* x = (sig == 0 ? rppg : ppg) + (size_t)row * LNUM;
  const int base = chunk * CHUNK;
  const float th = (float)thr[sig * NROW + row];

  stage(x, base, sh);
  __syncthreads();

  const int lane = threadIdx.x & 63;
  const int wid = threadIdx.x >> 6;
  const int woff = wid * SEG;
  double lsum = 0.0;
  int lcnt = 0;
  int first = -1, carry = -1;  // wave-uniform (every lane computes the same)
  for (int j = 0; j < ITER; ++j) {
    int pl = woff + j * 64 + lane;
    float v = sh[pl + 8];
    float w = sh[pl + 3];
#pragma unroll
    for (int k = 1; k < 11; ++k) w = fmaxf(w, sh[pl + 3 + k]);
    bool pk = (v == w) && (v > th);
    unsigned long long bal = __ballot(pk);
    if (pk) {
      unsigned long long below = bal & ((1ull << lane) - 1ull);
      if (below) {
        int prev_lane = 63 - __builtin_clzll(below);
        lsum += 1.0 / (double)(lane - prev_lane);
        ++lcnt;
      } else if (carry >= 0) {
        lsum += 1.0 / (double)(base + pl - carry);
        ++lcnt;
      }
    }
    if (bal) {
      int bb = base + woff + j * 64;
      if (first < 0) first = bb + __builtin_ctzll(bal);
      carry = bb + (63 - __builtin_clzll(bal));
    }
  }
  for (int off = 32; off > 0; off >>= 1) {
    lsum += __shfl_down(lsum, off);
    lcnt += __shfl_down(lcnt, off);
  }
  if (lane == 0) {
    Agg a; a.first = first; a.last = carry; a.c = lcnt; a.s = lsum;
    waggs[wid] = a;
  }
  __syncthreads();
  if (threadIdx.x == 0) {
    Agg a = waggs[0];
    for (int wq = 1; wq < NWAVE; ++wq) a = combine(a, waggs[wq]);
    cfirst[bid] = a.first; clast[bid] = a.last;
    ccnt[bid] = a.c; csum[bid] = a.s;
  }
}

// Combine the 512 chunk aggregates of each row (in order) -> hr per row.
__global__ void finalize_rows(const int* __restrict__ cfirst,
                              const int* __restrict__ clast,
                              const double* __restrict__ csum,
                              const int* __restrict__ ccnt,
                              const int* __restrict__ fsp,
                              double* __restrict__ hr) {
  __shared__ Agg aggs[NCHUNK];
  const int sr = blockIdx.x;  // 0..9
  const int t = threadIdx.x;  // 0..511
  Agg a;
  a.first = cfirst[sr * NCHUNK + t];
  a.last  = clast[sr * NCHUNK + t];
  a.s     = csum[sr * NCHUNK + t];
  a.c     = ccnt[sr * NCHUNK + t];
  aggs[t] = a;
  __syncthreads();
  for (int s = 1; s < NCHUNK; s <<= 1) {
    if ((t & (2 * s - 1)) == 0)
      aggs[t] = combine(aggs[t], aggs[t + s]);
    __syncthreads();
  }
  if (t == 0) {
    double fs = (double)fsp[0];
    hr[sr] = 60.0 * fs * aggs[0].s / (double)aggs[0].c;
  }
}

__global__ void final_kernel(const double* __restrict__ hr,
                             float* __restrict__ out) {
  double acc = 0.0;
  for (int r = 0; r < NROW; ++r) {
    double rh = hr[r];          // rppg rows (sig 0)
    double ph = hr[NROW + r];   // ppg rows (sig 1)
    acc += fabs(ph - rh) / ph;
  }
  out[0] = (float)(acc / (double)NROW);
}

}  // namespace

extern "C" void kernel_launch(void* const* d_in, const int* in_sizes, int n_in,
                              void* d_out, int out_size, void* d_ws, size_t ws_size,
                              hipStream_t stream) {
  const float* rppg = (const float*)d_in[0];
  const float* ppg  = (const float*)d_in[1];
  const int* fsp    = (const int*)d_in[2];
  float* out        = (float*)d_out;
  char* ws          = (char*)d_ws;

  // ws layout (8B-aligned blocks)
  double* psum  = (double*)(ws);                  // 5120*8 = 40960
  double* ppk   = (double*)(ws + 40960);          // 40960
  int*    pnpk  = (int*)(ws + 81920);             // 20480
  double* csum  = (double*)(ws + 102400);         // 40960
  int*    cfirst= (int*)(ws + 143360);            // 20480
  int*    clast = (int*)(ws + 163840);            // 20480
  int*    ccnt  = (int*)(ws + 184320);            // 20480
  double* thr   = (double*)(ws + 204800);         // 80
  double* hr    = (double*)(ws + 205824);         // 80
  // total ~206 KB

  stats_kernel<<<NBLK, TPB, 0, stream>>>(rppg, ppg, psum, ppk, pnpk);
  thresh_kernel<<<NSERIES, NCHUNK, 0, stream>>>(psum, ppk, pnpk, thr);
  gap_kernel<<<NBLK, TPB, 0, stream>>>(rppg, ppg, thr, cfirst, clast, csum, ccnt);
  finalize_rows<<<NSERIES, NCHUNK, 0, stream>>>(cfirst, clast, csum, ccnt, fsp, hr);
  final_kernel<<<1, 1, 0, stream>>>(hr, out);
  (void)in_sizes; (void)n_in; (void)out_size; (void)ws_size;
}